// Round 10
// baseline (272.133 us; speedup 1.0000x reference)
//
#include <hip/hip_runtime.h>
#include <hip/hip_bf16.h>

// FlowNetC correlation: B=4, C=256, H=W=96, PAD=MAX_DISP=20, STRIDE2=2, D=21.
// out[b, oy*21+ox, h, w] = (1/C) * sum_c x1[b,c,h,w] * x2[b,c,h+2oy-20,w+2ox-20]
//
// dx even -> split w by parity. Per (b,h,oy,par): out[i,e] = sum_c A[c,i]*B[c,i+e-10]
// (i=w>>1 in [0,48), e=ox). Band GEMM, MFMA 16x16x32 bf16.
//
// h-PAIRING (verified R2/R4): (h, oy=t) and (h+2, oy=t-1) share image
// x2[b, h+2t-20]: 2 MFMAs per B-fragment ds_read, one t-loop per pair.
//
// ROUND-10: hide the two serial exposures R0-R9 isolated (per-block chain is
// the limiter; residency/pipelining/traffic moves were neutral or negative):
//  (a) DEFERRED STORES via slab double-buffer: scatter(t) -> sl[k&1]; its
//      slab-read+global-store runs inside iteration k+1's compute region,
//      interleaved with MFMAs instead of serialized after a barrier.
//  (b) K-SPLIT batch: read ks0-3 frags -> MFMA -> read ks4-7 frags ->
//      __syncthreads -> STAGE(t+1) -> MFMA ks4-7 from registers. DMA flight
//      is covered by half the MFMA burst + scatter + deferred stores
//      (~600cyc) instead of just the old store phase (~300cyc). Only 12
//      fragments (48 VGPR) live across the barrier -> no spill (R8 lesson:
//      WRITE_SIZE > 63504 is the spill signature).
// R9 lesson kept: B stays in LDS (swizzled per-lane global reads shatter
// coalescing -> L2 request-rate bound). Barriers are plain __syncthreads()
// (R1: counted vmcnt == drain on this kernel).
// LDS = 48KB Bs + 32.6KB dual-slab x2 = 81,744B <= 81,920 -> 2 blocks/CU.

typedef __bf16 bf16x8 __attribute__((ext_vector_type(8)));
typedef float f32x4 __attribute__((ext_vector_type(4)));

#define B_ 4
#define C_ 256
#define H_ 96
#define W_ 96
#define NOFF 21
#define ROWS 96                         // rows per (b,h) image = 2 par * 48
#define IMG_ELEMS (ROWS * C_)           // 24576 ushorts = 48KB
#define X1T_ELEMS (B_ * H_ * IMG_ELEMS) // 9,437,184 ushorts

__device__ __forceinline__ unsigned short f32_to_bf16_rne(float f) {
    union { float f; unsigned u; } v; v.f = f;
    unsigned u = v.u;
    return (unsigned short)((u + 0x7fffu + ((u >> 16) & 1u)) >> 16);
}

__device__ __forceinline__ void gl2lds16(const void* g, void* l) {
    __builtin_amdgcn_global_load_lds(
        (const __attribute__((address_space(1))) void*)g,
        (__attribute__((address_space(3))) void*)l, 16, 0, 0);
}

// ---------------------------------------------------------------------------
// Prep: fp32 NCHW -> bf16 swizzled-transposed [b][h][row][chunk^(row&31)]
// row = par*48 + (w>>1), par = w&1. One block per (b,h,src,c-block-of-64).
// ---------------------------------------------------------------------------
__global__ __launch_bounds__(256) void prep_kernel(const float* __restrict__ x1,
                                                   const float* __restrict__ x2,
                                                   unsigned short* __restrict__ ws) {
    __shared__ float tile[96 * 65];   // [w][c_local], pitch 65: conflict-free
    int bid = blockIdx.x;
    int cblk  = bid & 3;
    int which = (bid >> 2) & 1;
    int bh    = bid >> 3;             // 0..383
    int h = bh % H_;
    int b = bh / H_;
    int c0 = cblk << 6;

    const float* src = (which ? x2 : x1) + ((size_t)(b * C_ + c0) * H_ + h) * W_;
    unsigned short* dst = ws + (size_t)which * X1T_ELEMS + (size_t)(b * H_ + h) * IMG_ELEMS;

    // Phase A: coalesced global reads -> LDS [w][c]
    for (int idx = threadIdx.x; idx < 64 * 96; idx += 256) {
        int c = idx / 96, w = idx - c * 96;
        tile[w * 65 + c] = src[c * (H_ * W_) + w];
    }
    __syncthreads();

    // Phase B: pack 8 c -> 16B store. Per row this c-block lands in one
    // contiguous 128B run (aligned 8-chunk group XOR'd by row bits). Dest-driven.
    for (int idx = threadIdx.x; idx < 96 * 8; idx += 256) {
        int row = idx >> 3, tp = idx & 7;
        int par = row / 48, i = row - par * 48;
        int w = 2 * i + par;
        int s = tp ^ (row & 7);                 // source chunk within c-block
        const float* fsrc = &tile[w * 65 + (s << 3)];
        unsigned pk[4];
#pragma unroll
        for (int e = 0; e < 4; ++e) {
            unsigned lo = f32_to_bf16_rne(fsrc[2 * e]);
            unsigned hi = f32_to_bf16_rne(fsrc[2 * e + 1]);
            pk[e] = lo | (hi << 16);
        }
        int ccp = (((c0 >> 3) ^ (row & 24)) + tp);   // swizzled chunk position
        *(uint4*)((char*)(dst + (size_t)row * C_) + (ccp << 4)) =
            make_uint4(pk[0], pk[1], pk[2], pk[3]);
    }
}

// ---------------------------------------------------------------------------
// Main: block = (b, h-pair, oy-quarter). 6 waves = (par, mt). 2 blocks/CU.
// ---------------------------------------------------------------------------
__global__ __launch_bounds__(384, 3) void corr_kernel(const unsigned short* __restrict__ ws,
                                                      float* __restrict__ out) {
    __shared__ unsigned short Bs[IMG_ELEMS];      // 48KB, single buffer
    __shared__ float sl[2][2][NOFF][97];          // DOUBLE-buffered dual slab
    static_assert(sizeof(Bs) + sizeof(sl) <= 81920, "need 2 blocks/CU");

    int bid = blockIdx.x;
    int xcd = bid & 7, sidx = bid >> 3;        // XCD-aware: each XCD gets (b, h-half)
    int b  = xcd >> 1;
    int p  = ((xcd & 1) ? 24 : 0) + (sidx >> 2);   // pair index [0,48)
    int og = sidx & 3;                              // oy quarter
    int g = p >> 1, par_h = p & 1;
    int hA = 4 * g + par_h, hB = hA + 2;            // {h mod4 in 0,1} x {+2}
    int olo = (og * NOFF) >> 2;                     // 0,5,10,15
    int ohi = ((og + 1) * NOFF) >> 2;               // 5,10,15,21

    int tid = threadIdx.x;
    int wv = tid >> 6, lane = tid & 63;
    int par = wv & 1, mt = wv >> 1;
    int i0 = mt << 4;
    int n = lane & 15, quad = lane >> 4;

    // Hoisted epilogue addressing: idx = tid + 384j, j < jcnt (5 or 6).
    int jcnt = 5 + (tid < 96 ? 1 : 0);
    int slotj[6], offj[6]; bool mj[6];
#pragma unroll
    for (int j = 0; j < 6; ++j) {
        int idx = tid + j * 384;
        int ox = idx / W_, w = idx - ox * W_;
        slotj[j] = ox * 97 + w;
        offj[j]  = ox * (H_ * W_) + w;
        int w2 = w + 2 * ox - 20;
        mj[j] = (w2 >= 0) & (w2 < W_);
    }

    // A fragments for BOTH rows: loaded once, reused for all t.
    int rowA = par * 48 + i0 + n;
    int keyA = rowA & 31;
    const unsigned short* AgA = ws + (size_t)(b * H_ + hA) * IMG_ELEMS + (size_t)rowA * C_;
    const unsigned short* AgB = ws + (size_t)(b * H_ + hB) * IMG_ELEMS + (size_t)rowA * C_;
    bf16x8 afA[8], afB[8];
#pragma unroll
    for (int ks = 0; ks < 8; ++ks) {
        int o = (((ks << 2) | quad) ^ keyA) << 3;
        afA[ks] = *(const bf16x8*)(AgA + o);
        afB[ks] = *(const bf16x8*)(AgB + o);
    }
    // Drain A loads before any DMA so no A-related wait lands inside the loop.
    asm volatile("" ::: "memory");
    __builtin_amdgcn_s_waitcnt(0);

    const unsigned short* Bimg = ws + (size_t)X1T_ELEMS + (size_t)(b * H_) * IMG_ELEMS;

    int rowB0 = par * 48 + n;          // u=0 (j 0..15)
    int rowB1 = rowB0 + 16;            // u=1
    int rowB2 = rowB0 + 32;            // u=2
    int keyB0 = rowB0 & 31, keyB1 = rowB1 & 31, keyB2 = rowB2 & 31;

    // Valid oy bands per row (clip h2 in range AND og quarter).
    int aLo = (hA <= 20) ? ((21 - hA) >> 1) : 0; if (aLo < olo) aLo = olo;
    int aHi = ((115 - hA) >> 1) + 1;             if (aHi > ohi) aHi = ohi;
    if (aHi < aLo) aHi = aLo;
    int bLo = (hB <= 20) ? ((21 - hB) >> 1) : 0; if (bLo < olo) bLo = olo;
    int bHi = ((115 - hB) >> 1) + 1;             if (bHi > ohi) bHi = ohi;
    if (bHi < bLo) bHi = bLo;

    // Image parameter t: planeA oy=t (t in [aLo,aHi)), planeB oy=t-1
    // (t in [bLo+1,bHi+1)). Union contiguous; every t has >=1 valid plane.
    int tlo, thi;
    bool ea = (aLo >= aHi), eb = (bLo >= bHi);
    if (ea && eb)      { tlo = 0; thi = 0; }
    else if (ea)       { tlo = bLo + 1; thi = bHi + 1; }
    else if (eb)       { tlo = aLo; thi = aHi; }
    else {
        tlo = (aLo < bLo + 1) ? aLo : bLo + 1;
        thi = (aHi > bHi + 1) ? aHi : bHi + 1;
    }
    int nv = thi - tlo;

    int wvoff  = wv * 8192;            // wave-uniform LDS base (6 waves x 8KB)
    int gmaoff = wvoff + lane * 16;    // per-lane global offset

#define STAGE(tt) do {                                                                \
    const char* Bg_ = (const char*)(Bimg + (size_t)(hA + 2 * (tt) - 20) * IMG_ELEMS); \
    _Pragma("unroll")                                                                 \
    for (int c = 0; c < 8; ++c)                                                       \
        gl2lds16(Bg_ + gmaoff + c * 1024, (char*)Bs + wvoff + c * 1024);              \
} while (0)

// Deferred store of image tt's two planes from slab buffer sb.
#define STORES(tt, sb) do {                                                           \
    bool okA_ = ((tt) >= aLo) & ((tt) < aHi);                                         \
    bool okB_ = ((tt) - 1 >= bLo) & ((tt) - 1 < bHi);                                 \
    int outbA_ = ((b * 441 + (tt) * NOFF) * H_ + hA) * W_;                            \
    int outbB_ = ((b * 441 + ((tt) - 1) * NOFF) * H_ + hB) * W_;                      \
    const float* sA_ = &sl[sb][0][0][0];                                              \
    const float* sB_ = &sl[sb][1][0][0];                                              \
    float vA_[6], vB_[6];                                                             \
    _Pragma("unroll")                                                                 \
    for (int j = 0; j < 6; ++j) if (j < jcnt) {                                       \
        vA_[j] = mj[j] ? sA_[slotj[j]] * (1.0f / 256.0f) : 0.0f;                      \
        vB_[j] = mj[j] ? sB_[slotj[j]] * (1.0f / 256.0f) : 0.0f;                      \
    }                                                                                 \
    if (okA_) {                                                                       \
        _Pragma("unroll")                                                             \
        for (int j = 0; j < 6; ++j) if (j < jcnt) out[outbA_ + offj[j]] = vA_[j];     \
    }                                                                                 \
    if (okB_) {                                                                       \
        _Pragma("unroll")                                                             \
        for (int j = 0; j < 6; ++j) if (j < jcnt) out[outbB_ + offj[j]] = vB_[j];     \
    }                                                                                 \
} while (0)

    // Prologue: stage first image, then zero-fill OOB planes while it flies.
    if (nv > 0) STAGE(tlo);
    asm volatile("" ::: "memory");   // pin: zero-fill stores stay after the STAGE

    for (int oy = olo; oy < ohi; ++oy) {
        if (oy < aLo || oy >= aHi) {
            int outb = ((b * 441 + oy * NOFF) * H_ + hA) * W_;
#pragma unroll
            for (int j = 0; j < 6; ++j) if (j < jcnt) out[outb + offj[j]] = 0.0f;
        }
        if (oy < bLo || oy >= bHi) {
            int outb = ((b * 441 + oy * NOFF) * H_ + hB) * W_;
#pragma unroll
            for (int j = 0; j < 6; ++j) if (j < jcnt) out[outb + offj[j]] = 0.0f;
        }
    }

    for (int k = 0; k < nv; ++k) {
        int t = tlo + k;

        // bar_b: DMA for image t landed (vmcnt drain) + prior slab ds_reads done.
        __syncthreads();

        const char* Bsb = (const char*)Bs;
        f32x4 aA0 = {0.f,0.f,0.f,0.f}, aA1 = {0.f,0.f,0.f,0.f}, aA2 = {0.f,0.f,0.f,0.f};
        f32x4 aB0 = {0.f,0.f,0.f,0.f}, aB1 = {0.f,0.f,0.f,0.f}, aB2 = {0.f,0.f,0.f,0.f};
        bf16x8 g0[4], g1[4], g2[4];    // second K-half fragments (live across bar_e)

        // First K-half: read + MFMA (frags die before bar_e). Then read the
        // second K-half into g[] so Bs is fully consumed by bar_e.
        __builtin_amdgcn_s_setprio(1);
        if (mt == 0) {
#pragma unroll
            for (int ks = 0; ks < 4; ++ks) {
                int ci = (ks << 2) | quad;
                bf16x8 f0 = *(const bf16x8*)(Bsb + rowB0 * 512 + ((ci ^ keyB0) << 4));
                bf16x8 f1 = *(const bf16x8*)(Bsb + rowB1 * 512 + ((ci ^ keyB1) << 4));
                aA0 = __builtin_amdgcn_mfma_f32_16x16x32_bf16(afA[ks], f0, aA0, 0, 0, 0);
                aA1 = __builtin_amdgcn_mfma_f32_16x16x32_bf16(afA[ks], f1, aA1, 0, 0, 0);
                aB0 = __builtin_amdgcn_mfma_f32_16x16x32_bf16(afB[ks], f0, aB0, 0, 0, 0);
                aB1 = __builtin_amdgcn_mfma_f32_16x16x32_bf16(afB[ks], f1, aB1, 0, 0, 0);
            }
#pragma unroll
            for (int ks = 0; ks < 4; ++ks) {
                int ci = ((ks + 4) << 2) | quad;
                g0[ks] = *(const bf16x8*)(Bsb + rowB0 * 512 + ((ci ^ keyB0) << 4));
                g1[ks] = *(const bf16x8*)(Bsb + rowB1 * 512 + ((ci ^ keyB1) << 4));
            }
        } else if (mt == 1) {
#pragma unroll
            for (int ks = 0; ks < 4; ++ks) {
                int ci = (ks << 2) | quad;
                bf16x8 f0 = *(const bf16x8*)(Bsb + rowB0 * 512 + ((ci ^ keyB0) << 4));
                bf16x8 f1 = *(const bf16x8*)(Bsb + rowB1 * 512 + ((ci ^ keyB1) << 4));
                bf16x8 f2 = *(const bf16x8*)(Bsb + rowB2 * 512 + ((ci ^ keyB2) << 4));
                aA0 = __builtin_amdgcn_mfma_f32_16x16x32_bf16(afA[ks], f0, aA0, 0, 0, 0);
                aA1 = __builtin_amdgcn_mfma_f32_16x16x32_bf16(afA[ks], f1, aA1, 0, 0, 0);
                aA2 = __builtin_amdgcn_mfma_f32_16x16x32_bf16(afA[ks], f2, aA2, 0, 0, 0);
                aB0 = __builtin_amdgcn_mfma_f32_16x16x32_bf16(afB[ks], f0, aB0, 0, 0, 0);
                aB1 = __builtin_amdgcn_mfma_f32_16x16x32_bf16(afB[ks], f1, aB1, 0, 0, 0);
                aB2 = __builtin_amdgcn_mfma_f32_16x16x32_bf16(afB[ks], f2, aB2, 0, 0, 0);
            }
#pragma unroll
            for (int ks = 0; ks < 4; ++ks) {
                int ci = ((ks + 4) << 2) | quad;
                g0[ks] = *(const bf16x8*)(Bsb + rowB0 * 512 + ((ci ^ keyB0) << 4));
                g1[ks] = *(const bf16x8*)(Bsb + rowB1 * 512 + ((ci ^ keyB1) << 4));
                g2[ks] = *(const bf16x8*)(Bsb + rowB2 * 512 + ((ci ^ keyB2) << 4));
            }
        } else {
#pragma unroll
            for (int ks = 0; ks < 4; ++ks) {
                int ci = (ks << 2) | quad;
                bf16x8 f1 = *(const bf16x8*)(Bsb + rowB1 * 512 + ((ci ^ keyB1) << 4));
                bf16x8 f2 = *(const bf16x8*)(Bsb + rowB2 * 512 + ((ci ^ keyB2) << 4));
                aA1 = __builtin_amdgcn_mfma_f32_16x16x32_bf16(afA[ks], f1, aA1, 0, 0, 0);
                aA2 = __builtin_amdgcn_mfma_f32_16x16x32_bf16(afA[ks], f2, aA2, 0, 0, 0);
                aB1 = __builtin_amdgcn_mfma_f32_16x16x32_bf16(afB[ks], f1, aB1, 0, 0, 0);
                aB2 = __builtin_amdgcn_mfma_f32_16x16x32_bf16(afB[ks], f2, aB2, 0, 0, 0);
            }
#pragma unroll
            for (int ks = 0; ks < 4; ++ks) {
                int ci = ((ks + 4) << 2) | quad;
                g1[ks] = *(const bf16x8*)(Bsb + rowB1 * 512 + ((ci ^ keyB1) << 4));
                g2[ks] = *(const bf16x8*)(Bsb + rowB2 * 512 + ((ci ^ keyB2) << 4));
            }
        }

        // bar_e: all ds_reads of Bs complete (lgkm drained) -> buffer free.
        __syncthreads();

        // STAGE early: DMA of t+1 flies under the second-half MFMA burst,
        // the scatter, and the deferred stores of image t-1.
        if (k + 1 < nv) STAGE(t + 1);

        // Second K-half MFMA from registers (no LDS dependency).
        if (mt == 0) {
#pragma unroll
            for (int ks = 0; ks < 4; ++ks) {
                aA0 = __builtin_amdgcn_mfma_f32_16x16x32_bf16(afA[ks + 4], g0[ks], aA0, 0, 0, 0);
                aA1 = __builtin_amdgcn_mfma_f32_16x16x32_bf16(afA[ks + 4], g1[ks], aA1, 0, 0, 0);
                aB0 = __builtin_amdgcn_mfma_f32_16x16x32_bf16(afB[ks + 4], g0[ks], aB0, 0, 0, 0);
                aB1 = __builtin_amdgcn_mfma_f32_16x16x32_bf16(afB[ks + 4], g1[ks], aB1, 0, 0, 0);
            }
        } else if (mt == 1) {
#pragma unroll
            for (int ks = 0; ks < 4; ++ks) {
                aA0 = __builtin_amdgcn_mfma_f32_16x16x32_bf16(afA[ks + 4], g0[ks], aA0, 0, 0, 0);
                aA1 = __builtin_amdgcn_mfma_f32_16x16x32_bf16(afA[ks + 4], g1[ks], aA1, 0, 0, 0);
                aA2 = __builtin_amdgcn_mfma_f32_16x16x32_bf16(afA[ks + 4], g2[ks], aA2, 0, 0, 0);
                aB0 = __builtin_amdgcn_mfma_f32_16x16x32_bf16(afB[ks + 4], g0[ks], aB0, 0, 0, 0);
                aB1 = __builtin_amdgcn_mfma_f32_16x16x32_bf16(afB[ks + 4], g1[ks], aB1, 0, 0, 0);
                aB2 = __builtin_amdgcn_mfma_f32_16x16x32_bf16(afB[ks + 4], g2[ks], aB2, 0, 0, 0);
            }
        } else {
#pragma unroll
            for (int ks = 0; ks < 4; ++ks) {
                aA1 = __builtin_amdgcn_mfma_f32_16x16x32_bf16(afA[ks + 4], g1[ks], aA1, 0, 0, 0);
                aA2 = __builtin_amdgcn_mfma_f32_16x16x32_bf16(afA[ks + 4], g2[ks], aA2, 0, 0, 0);
                aB1 = __builtin_amdgcn_mfma_f32_16x16x32_bf16(afB[ks + 4], g1[ks], aB1, 0, 0, 0);
                aB2 = __builtin_amdgcn_mfma_f32_16x16x32_bf16(afB[ks + 4], g2[ks], aB2, 0, 0, 0);
            }
        }
        __builtin_amdgcn_s_setprio(0);

        // Scatter image t into slab buffer k&1 (published at next bar_b).
        // C/D: col n = lane&15, row m = quad*4+r. ox = 16*(u+1) + n - (i0+m) - 6.
        {
            float (*slw)[NOFF][97] = sl[k & 1];
#pragma unroll
            for (int r = 0; r < 4; ++r) {
                int m = (quad << 2) + r;
                int w = 2 * (i0 + m) + par;
                int oxb = n - i0 - m - 6;
                if (mt != 2) { int ox = 16 + oxb; if (ox >= 0 && ox < NOFF) { slw[0][ox][w] = aA0[r]; slw[1][ox][w] = aB0[r]; } }
                {             int ox = 32 + oxb; if (ox >= 0 && ox < NOFF) { slw[0][ox][w] = aA1[r]; slw[1][ox][w] = aB1[r]; } }
                if (mt != 0) { int ox = 48 + oxb; if (ox >= 0 && ox < NOFF) { slw[0][ox][w] = aA2[r]; slw[1][ox][w] = aB2[r]; } }
            }
        }

        // Deferred stores of image t-1 (scattered at iter k-1 into buffer
        // (k-1)&1, published by this iteration's bar_b). Interleaves with the
        // MFMA/scatter region above at the scheduler's discretion.
        if (k >= 1) STORES(t - 1, (k ^ 1) & 1);
    }

    // Epilogue: publish last scatter, then store the final image.
    if (nv > 0) {
        __syncthreads();
        STORES(thi - 1, (nv ^ 1) & 1);
    }
#undef STORES
#undef STAGE
}

// ---------------------------------------------------------------------------
// Fallback (ws too small): direct fp32, slow but correct.
// ---------------------------------------------------------------------------
__global__ __launch_bounds__(256) void corr_fallback(const float* __restrict__ x1,
                                                     const float* __restrict__ x2,
                                                     float* __restrict__ out) {
    int bid = blockIdx.x;
    int oy = bid % NOFF, h = (bid / NOFF) % H_, b = bid / (NOFF * H_);
    int dy = 2 * oy - 20, h2 = h + dy;
    int outbase = ((b * 441 + oy * NOFF) * H_ + h) * W_;
    for (int idx = threadIdx.x; idx < NOFF * W_; idx += 256) {
        int ox = idx / W_, w = idx % W_;
        float acc = 0.f;
        int w2 = w + 2 * ox - 20;
        if (h2 >= 0 && h2 < H_ && w2 >= 0 && w2 < W_) {
            const float* p1 = x1 + (size_t)b * C_ * H_ * W_ + h * W_ + w;
            const float* p2 = x2 + (size_t)b * C_ * H_ * W_ + h2 * W_ + w2;
            for (int c = 0; c < C_; ++c) acc += p1[c * (H_ * W_)] * p2[c * (H_ * W_)];
        }
        out[outbase + ox * (H_ * W_) + w] = acc * (1.0f / 256.0f);
    }
}

extern "C" void kernel_launch(void* const* d_in, const int* in_sizes, int n_in,
                              void* d_out, int out_size, void* d_ws, size_t ws_size,
                              hipStream_t stream) {
    const float* x1 = (const float*)d_in[0];
    const float* x2 = (const float*)d_in[1];
    float* out = (float*)d_out;

    size_t need = (size_t)2 * X1T_ELEMS * sizeof(unsigned short);  // 37.7 MB
    if (ws_size >= need) {
        unsigned short* ws = (unsigned short*)d_ws;
        prep_kernel<<<B_ * H_ * 2 * 4, 256, 0, stream>>>(x1, x2, ws);
        corr_kernel<<<768, 384, 0, stream>>>(ws, out);
    } else {
        corr_fallback<<<B_ * H_ * NOFF, 256, 0, stream>>>(x1, x2, out);
    }
}

// Round 11
// 252.785 us; speedup vs baseline: 1.0765x; 1.0765x over previous
//
#include <hip/hip_runtime.h>
#include <hip/hip_bf16.h>

// FlowNetC correlation: B=4, C=256, H=W=96, PAD=MAX_DISP=20, STRIDE2=2, D=21.
// out[b, oy*21+ox, h, w] = (1/C) * sum_c x1[b,c,h,w] * x2[b,c,h+2oy-20,w+2ox-20]
//
// dx even -> split w by parity. Per (b,h,oy,par): out[i,e] = sum_c A[c,i]*B[c,i+e-10]
// (i=w>>1 in [0,48), e=ox). Band GEMM, MFMA 16x16x32 bf16.
//
// ROUND-11 = ROUND-8 GEOMETRY + ROUND-4 CODEGEN STYLE. h-TRIPLE: planes
// (hA, oy=t), (hA+2, t-1), (hA+4, t-2) share image x2[b, hA+2t-20]: 3 MFMAs
// per B-fragment ds_read, 1 image DMA + 2 barriers per 3 planes. Iterations
// halve vs h-pair (3712 vs 7219 block-iters) on the saturated LDS/DMA pipe.
// Grid 512 = exactly 2 blocks/CU (73.6KB LDS), zero dispatch tail.
//
// WHY R8 REGRESSED (and this won't): R8 used f32x4 acc[3][3] / bf16x8 bfr[3]
// arrays indexed under a runtime-varying guard (useu[u]) -> rule-#20 scratch
// demotion -> WRITE_SIZE +16MB spill traffic. R10 confirmed the signature at
// scale (138MB). This version uses 9 NAMED f32x4 accumulators + mt-branched
// straight-line MFMA bursts + constant-indexed fragment arrays — exactly the
// pattern R4 compiles to 84 VGPR with zero spill. WRITE_SIZE == 63504 is the
// pass/fail detector.
//
// vmcnt ledger (per wave): P=8 gl2lds per image; at (b) of iter k+1 the
// outstanding VMEM list is P(k+1) [oldest, 8] then iter-k stores. vmcnt(5)
// waits until <=5 outstanding; retirement is IN-ORDER, so all 8 P retired.
// k==0 uses vmcnt(0) (drains prologue STAGE + zero-fill stores once).
//
// Band logic (verified in R8, which PASSED): plane j valid for oy in
// [Loj, Hij); t-interval [Loj+j, Hij+j); union contiguous, every t has >=1
// valid plane => DMA row h2 = hA+2t-20 always in [0,96).
//
// Global layout XOR-swizzle per row (chunk' = chunk ^ (row&31)): wave's
// ds_read_b128 at 512B row stride is conflict-free; flat DMA copy preserves
// the per-row chunk permutation.

typedef __bf16 bf16x8 __attribute__((ext_vector_type(8)));
typedef float f32x4 __attribute__((ext_vector_type(4)));

#define B_ 4
#define C_ 256
#define H_ 96
#define W_ 96
#define NOFF 21
#define ROWS 96                         // rows per (b,h) image = 2 par * 48
#define IMG_ELEMS (ROWS * C_)           // 24576 ushorts = 48KB
#define X1T_ELEMS (B_ * H_ * IMG_ELEMS) // 9,437,184 ushorts

__device__ __forceinline__ unsigned short f32_to_bf16_rne(float f) {
    union { float f; unsigned u; } v; v.f = f;
    unsigned u = v.u;
    return (unsigned short)((u + 0x7fffu + ((u >> 16) & 1u)) >> 16);
}

__device__ __forceinline__ void gl2lds16(const void* g, void* l) {
    __builtin_amdgcn_global_load_lds(
        (const __attribute__((address_space(1))) void*)g,
        (__attribute__((address_space(3))) void*)l, 16, 0, 0);
}

// ---------------------------------------------------------------------------
// Prep: fp32 NCHW -> bf16 swizzled-transposed [b][h][row][chunk^(row&31)]
// row = par*48 + (w>>1), par = w&1. One block per (b,h,src,c-block-of-64).
// ---------------------------------------------------------------------------
__global__ __launch_bounds__(256) void prep_kernel(const float* __restrict__ x1,
                                                   const float* __restrict__ x2,
                                                   unsigned short* __restrict__ ws) {
    __shared__ float tile[96 * 65];   // [w][c_local], pitch 65: conflict-free
    int bid = blockIdx.x;
    int cblk  = bid & 3;
    int which = (bid >> 2) & 1;
    int bh    = bid >> 3;             // 0..383
    int h = bh % H_;
    int b = bh / H_;
    int c0 = cblk << 6;

    const float* src = (which ? x2 : x1) + ((size_t)(b * C_ + c0) * H_ + h) * W_;
    unsigned short* dst = ws + (size_t)which * X1T_ELEMS + (size_t)(b * H_ + h) * IMG_ELEMS;

    // Phase A: coalesced global reads -> LDS [w][c]
    for (int idx = threadIdx.x; idx < 64 * 96; idx += 256) {
        int c = idx / 96, w = idx - c * 96;
        tile[w * 65 + c] = src[c * (H_ * W_) + w];
    }
    __syncthreads();

    // Phase B: pack 8 c -> 16B store. Per row this c-block lands in one
    // contiguous 128B run (aligned 8-chunk group XOR'd by row bits). Dest-driven.
    for (int idx = threadIdx.x; idx < 96 * 8; idx += 256) {
        int row = idx >> 3, tp = idx & 7;
        int par = row / 48, i = row - par * 48;
        int w = 2 * i + par;
        int s = tp ^ (row & 7);                 // source chunk within c-block
        const float* fsrc = &tile[w * 65 + (s << 3)];
        unsigned pk[4];
#pragma unroll
        for (int e = 0; e < 4; ++e) {
            unsigned lo = f32_to_bf16_rne(fsrc[2 * e]);
            unsigned hi = f32_to_bf16_rne(fsrc[2 * e + 1]);
            pk[e] = lo | (hi << 16);
        }
        int ccp = (((c0 >> 3) ^ (row & 24)) + tp);   // swizzled chunk position
        *(uint4*)((char*)(dst + (size_t)row * C_) + (ccp << 4)) =
            make_uint4(pk[0], pk[1], pk[2], pk[3]);
    }
}

// ---------------------------------------------------------------------------
// Main: block = (b, h-triple, oy-quarter). 6 waves = (par, mt). 2 blocks/CU.
// ---------------------------------------------------------------------------
__global__ __launch_bounds__(384, 3) void corr_kernel(const unsigned short* __restrict__ ws,
                                                      float* __restrict__ out) {
    __shared__ unsigned short Bs[IMG_ELEMS];      // 48KB, single buffer
    __shared__ float sl[3][NOFF][97];             // triple transpose slab (24.4KB)
    static_assert(sizeof(Bs) + sizeof(sl) <= 81920, "need 2 blocks/CU");

    int bid = blockIdx.x;                      // grid = 512
    int xcd = bid & 7, sidx = bid >> 3;        // XCD-aware: each XCD gets (b, h-half)
    int b  = xcd >> 1;
    int hh = xcd & 1;
    int og = sidx & 3;                         // oy quarter
    int tq = sidx >> 2;                        // triple-in-half [0,16)
    int k8 = tq >> 1, ph = tq & 1;
    int hA = 48 * hh + 6 * k8 + ph;            // planes hA, hA+2, hA+4
    int olo = (og * NOFF) >> 2;                // 0,5,10,15
    int ohi = ((og + 1) * NOFF) >> 2;          // 5,10,15,21

    int tid = threadIdx.x;
    int wv = tid >> 6, lane = tid & 63;
    int par = wv & 1, mt = wv >> 1;
    int i0 = mt << 4;
    int n = lane & 15, quad = lane >> 4;

    // Hoisted epilogue addressing: idx = tid + 384j, j < jcnt (5 or 6).
    int jcnt = 5 + (tid < 96 ? 1 : 0);
    int slotj[6], offj[6]; bool mj[6];
#pragma unroll
    for (int j = 0; j < 6; ++j) {
        int idx = tid + j * 384;
        int ox = idx / W_, w = idx - ox * W_;
        slotj[j] = ox * 97 + w;
        offj[j]  = ox * (H_ * W_) + w;
        int w2 = w + 2 * ox - 20;
        mj[j] = (w2 >= 0) & (w2 < W_);
    }

    // A fragments for all 3 planes: loaded once, reused for all t.
    // Constant-indexed arrays only (rule #20: no runtime-guarded indexing).
    int rowA = par * 48 + i0 + n;
    int keyA = rowA & 31;
    const unsigned short* AgA = ws + (size_t)(b * H_ + hA)     * IMG_ELEMS + (size_t)rowA * C_;
    const unsigned short* AgB = ws + (size_t)(b * H_ + hA + 2) * IMG_ELEMS + (size_t)rowA * C_;
    const unsigned short* AgC = ws + (size_t)(b * H_ + hA + 4) * IMG_ELEMS + (size_t)rowA * C_;
    bf16x8 afA[8], afB[8], afC[8];
#pragma unroll
    for (int ks = 0; ks < 8; ++ks) {
        int o = (((ks << 2) | quad) ^ keyA) << 3;
        afA[ks] = *(const bf16x8*)(AgA + o);
        afB[ks] = *(const bf16x8*)(AgB + o);
        afC[ks] = *(const bf16x8*)(AgC + o);
    }
    // Drain A loads before any DMA so no A-related wait lands inside the loop.
    asm volatile("" ::: "memory");
    __builtin_amdgcn_s_waitcnt(0);

    const unsigned short* Bimg = ws + (size_t)X1T_ELEMS + (size_t)(b * H_) * IMG_ELEMS;

    int rowB0 = par * 48 + n;          // u=0 (j 0..15)
    int rowB1 = rowB0 + 16;            // u=1
    int rowB2 = rowB0 + 32;            // u=2
    int keyB0 = rowB0 & 31, keyB1 = rowB1 & 31, keyB2 = rowB2 & 31;

    // Valid oy bands per plane j (h_j = hA+2j), clipped to the og quarter.
    int Loj[3], Hij[3];
    int tlo = 1 << 30, thi = -(1 << 30);
#pragma unroll
    for (int j = 0; j < 3; ++j) {
        int hj = hA + 2 * j;
        int lo = (hj >= 21) ? 0 : ((21 - hj) >> 1);
        int hi = ((115 - hj) >> 1) + 1;
        if (lo < olo) lo = olo;
        if (hi > ohi) hi = ohi;
        Loj[j] = lo; Hij[j] = hi;
        if (lo < hi) {
            if (lo + j < tlo) tlo = lo + j;
            if (hi + j > thi) thi = hi + j;
        }
    }
    int nv = thi - tlo; if (nv < 0) nv = 0;

    int wvoff  = wv * 8192;            // wave-uniform LDS base (6 waves x 8KB)
    int gmaoff = wvoff + lane * 16;    // per-lane global offset

#define STAGE(tt) do {                                                                \
    const char* Bg_ = (const char*)(Bimg + (size_t)(hA + 2 * (tt) - 20) * IMG_ELEMS); \
    _Pragma("unroll")                                                                 \
    for (int c = 0; c < 8; ++c)                                                       \
        gl2lds16(Bg_ + gmaoff + c * 1024, (char*)Bs + wvoff + c * 1024);              \
} while (0)

    // Prologue: stage first image, then zero-fill OOB planes while it flies.
    if (nv > 0) STAGE(tlo);
    asm volatile("" ::: "memory");   // pin: zero-fill stores stay after the STAGE

#pragma unroll
    for (int pl = 0; pl < 3; ++pl) {
        int hp = hA + 2 * pl;
        for (int oy = olo; oy < ohi; ++oy) {
            if (oy >= Loj[pl] && oy < Hij[pl]) continue;
            int outb = ((b * 441 + oy * NOFF) * H_ + hp) * W_;
#pragma unroll
            for (int j = 0; j < 6; ++j) if (j < jcnt) out[outb + offj[j]] = 0.0f;
        }
    }

    for (int k = 0; k < nv; ++k) {
        int t = tlo + k;

        // (b) wait for this image's DMA + barrier. Steady: vmcnt(5) retires
        // P(k) (in-order retirement: the 8 DMA ops are oldest).
        if (k == 0) asm volatile("s_waitcnt vmcnt(0)\ns_barrier" ::: "memory");
        else        asm volatile("s_waitcnt vmcnt(5)\ns_barrier" ::: "memory");

        // (d) batch-load B fragments, then straight-line MFMA burst for all
        // 3 A-sets. NAMED accumulators, mt-branched (R4 codegen pattern).
        const char* Bsb = (const char*)Bs;
        f32x4 aA0 = {0.f,0.f,0.f,0.f}, aA1 = {0.f,0.f,0.f,0.f}, aA2 = {0.f,0.f,0.f,0.f};
        f32x4 aB0 = {0.f,0.f,0.f,0.f}, aB1 = {0.f,0.f,0.f,0.f}, aB2 = {0.f,0.f,0.f,0.f};
        f32x4 aC0 = {0.f,0.f,0.f,0.f}, aC1 = {0.f,0.f,0.f,0.f}, aC2 = {0.f,0.f,0.f,0.f};

        __builtin_amdgcn_s_setprio(1);
        if (mt == 0) {
            bf16x8 f0[8], f1[8];
#pragma unroll
            for (int ks = 0; ks < 8; ++ks) {
                int ci = (ks << 2) | quad;
                f0[ks] = *(const bf16x8*)(Bsb + rowB0 * 512 + ((ci ^ keyB0) << 4));
                f1[ks] = *(const bf16x8*)(Bsb + rowB1 * 512 + ((ci ^ keyB1) << 4));
            }
#pragma unroll
            for (int ks = 0; ks < 8; ++ks) {
                aA0 = __builtin_amdgcn_mfma_f32_16x16x32_bf16(afA[ks], f0[ks], aA0, 0, 0, 0);
                aA1 = __builtin_amdgcn_mfma_f32_16x16x32_bf16(afA[ks], f1[ks], aA1, 0, 0, 0);
                aB0 = __builtin_amdgcn_mfma_f32_16x16x32_bf16(afB[ks], f0[ks], aB0, 0, 0, 0);
                aB1 = __builtin_amdgcn_mfma_f32_16x16x32_bf16(afB[ks], f1[ks], aB1, 0, 0, 0);
                aC0 = __builtin_amdgcn_mfma_f32_16x16x32_bf16(afC[ks], f0[ks], aC0, 0, 0, 0);
                aC1 = __builtin_amdgcn_mfma_f32_16x16x32_bf16(afC[ks], f1[ks], aC1, 0, 0, 0);
            }
        } else if (mt == 1) {
            bf16x8 f0[8], f1[8], f2[8];
#pragma unroll
            for (int ks = 0; ks < 8; ++ks) {
                int ci = (ks << 2) | quad;
                f0[ks] = *(const bf16x8*)(Bsb + rowB0 * 512 + ((ci ^ keyB0) << 4));
                f1[ks] = *(const bf16x8*)(Bsb + rowB1 * 512 + ((ci ^ keyB1) << 4));
                f2[ks] = *(const bf16x8*)(Bsb + rowB2 * 512 + ((ci ^ keyB2) << 4));
            }
#pragma unroll
            for (int ks = 0; ks < 8; ++ks) {
                aA0 = __builtin_amdgcn_mfma_f32_16x16x32_bf16(afA[ks], f0[ks], aA0, 0, 0, 0);
                aA1 = __builtin_amdgcn_mfma_f32_16x16x32_bf16(afA[ks], f1[ks], aA1, 0, 0, 0);
                aA2 = __builtin_amdgcn_mfma_f32_16x16x32_bf16(afA[ks], f2[ks], aA2, 0, 0, 0);
                aB0 = __builtin_amdgcn_mfma_f32_16x16x32_bf16(afB[ks], f0[ks], aB0, 0, 0, 0);
                aB1 = __builtin_amdgcn_mfma_f32_16x16x32_bf16(afB[ks], f1[ks], aB1, 0, 0, 0);
                aB2 = __builtin_amdgcn_mfma_f32_16x16x32_bf16(afB[ks], f2[ks], aB2, 0, 0, 0);
                aC0 = __builtin_amdgcn_mfma_f32_16x16x32_bf16(afC[ks], f0[ks], aC0, 0, 0, 0);
                aC1 = __builtin_amdgcn_mfma_f32_16x16x32_bf16(afC[ks], f1[ks], aC1, 0, 0, 0);
                aC2 = __builtin_amdgcn_mfma_f32_16x16x32_bf16(afC[ks], f2[ks], aC2, 0, 0, 0);
            }
        } else {
            bf16x8 f1[8], f2[8];
#pragma unroll
            for (int ks = 0; ks < 8; ++ks) {
                int ci = (ks << 2) | quad;
                f1[ks] = *(const bf16x8*)(Bsb + rowB1 * 512 + ((ci ^ keyB1) << 4));
                f2[ks] = *(const bf16x8*)(Bsb + rowB2 * 512 + ((ci ^ keyB2) << 4));
            }
#pragma unroll
            for (int ks = 0; ks < 8; ++ks) {
                aA1 = __builtin_amdgcn_mfma_f32_16x16x32_bf16(afA[ks], f1[ks], aA1, 0, 0, 0);
                aA2 = __builtin_amdgcn_mfma_f32_16x16x32_bf16(afA[ks], f2[ks], aA2, 0, 0, 0);
                aB1 = __builtin_amdgcn_mfma_f32_16x16x32_bf16(afB[ks], f1[ks], aB1, 0, 0, 0);
                aB2 = __builtin_amdgcn_mfma_f32_16x16x32_bf16(afB[ks], f2[ks], aB2, 0, 0, 0);
                aC1 = __builtin_amdgcn_mfma_f32_16x16x32_bf16(afC[ks], f1[ks], aC1, 0, 0, 0);
                aC2 = __builtin_amdgcn_mfma_f32_16x16x32_bf16(afC[ks], f2[ks], aC2, 0, 0, 0);
            }
        }
        __builtin_amdgcn_s_setprio(0);

        // Scatter all 3 planes (in-band cell set is t-invariant, so stale
        // entries are exactly the out-of-range masked ones).
        // C/D: col n = lane&15, row m = quad*4+r. ox = 16*(u+1) + n - (i0+m) - 6.
#pragma unroll
        for (int r = 0; r < 4; ++r) {
            int m = (quad << 2) + r;
            int w = 2 * (i0 + m) + par;
            int oxb = n - i0 - m - 6;
            if (mt != 2) { int ox = 16 + oxb; if (ox >= 0 && ox < NOFF) { sl[0][ox][w] = aA0[r]; sl[1][ox][w] = aB0[r]; sl[2][ox][w] = aC0[r]; } }
            {             int ox = 32 + oxb; if (ox >= 0 && ox < NOFF) { sl[0][ox][w] = aA1[r]; sl[1][ox][w] = aB1[r]; sl[2][ox][w] = aC1[r]; } }
            if (mt != 0) { int ox = 48 + oxb; if (ox >= 0 && ox < NOFF) { sl[0][ox][w] = aA2[r]; sl[1][ox][w] = aB2[r]; sl[2][ox][w] = aC2[r]; } }
        }

        // (e) LDS drain + barrier: slab visible; ALL waves done reading Bs,
        // so the buffer is free for the next image.
        asm volatile("s_waitcnt lgkmcnt(0)\ns_barrier" ::: "memory");

        // (g) stage image t+1 into the freed buffer; flies under this block's
        // store phase + the co-resident block's compute phase.
        if (k + 1 < nv) STAGE(t + 1);
        asm volatile("" ::: "memory");   // pin: stores below stay after the STAGE

        // (f) batched slab reads, then plane-masked stores (block-uniform
        // gates; >=5 stores per wave per valid plane; >=1 valid plane per t).
#pragma unroll
        for (int pl = 0; pl < 3; ++pl) {
            int oyp = t - pl;
            if (oyp < Loj[pl] || oyp >= Hij[pl]) continue;
            int outb = ((b * 441 + oyp * NOFF) * H_ + (hA + 2 * pl)) * W_;
            const float* slp = &sl[pl][0][0];
            float v[6];
#pragma unroll
            for (int j = 0; j < 6; ++j) if (j < jcnt)
                v[j] = mj[j] ? slp[slotj[j]] * (1.0f / 256.0f) : 0.0f;
#pragma unroll
            for (int j = 0; j < 6; ++j) if (j < jcnt)
                out[outb + offj[j]] = v[j];
        }
    }
#undef STAGE
}

// ---------------------------------------------------------------------------
// Fallback (ws too small): direct fp32, slow but correct.
// ---------------------------------------------------------------------------
__global__ __launch_bounds__(256) void corr_fallback(const float* __restrict__ x1,
                                                     const float* __restrict__ x2,
                                                     float* __restrict__ out) {
    int bid = blockIdx.x;
    int oy = bid % NOFF, h = (bid / NOFF) % H_, b = bid / (NOFF * H_);
    int dy = 2 * oy - 20, h2 = h + dy;
    int outbase = ((b * 441 + oy * NOFF) * H_ + h) * W_;
    for (int idx = threadIdx.x; idx < NOFF * W_; idx += 256) {
        int ox = idx / W_, w = idx % W_;
        float acc = 0.f;
        int w2 = w + 2 * ox - 20;
        if (h2 >= 0 && h2 < H_ && w2 >= 0 && w2 < W_) {
            const float* p1 = x1 + (size_t)b * C_ * H_ * W_ + h * W_ + w;
            const float* p2 = x2 + (size_t)b * C_ * H_ * W_ + h2 * W_ + w2;
            for (int c = 0; c < C_; ++c) acc += p1[c * (H_ * W_)] * p2[c * (H_ * W_)];
        }
        out[outbase + ox * (H_ * W_) + w] = acc * (1.0f / 256.0f);
    }
}

extern "C" void kernel_launch(void* const* d_in, const int* in_sizes, int n_in,
                              void* d_out, int out_size, void* d_ws, size_t ws_size,
                              hipStream_t stream) {
    const float* x1 = (const float*)d_in[0];
    const float* x2 = (const float*)d_in[1];
    float* out = (float*)d_out;

    size_t need = (size_t)2 * X1T_ELEMS * sizeof(unsigned short);  // 37.7 MB
    if (ws_size >= need) {
        unsigned short* ws = (unsigned short*)d_ws;
        prep_kernel<<<B_ * H_ * 2 * 4, 256, 0, stream>>>(x1, x2, ws);
        corr_kernel<<<512, 384, 0, stream>>>(ws, out);
    } else {
        corr_fallback<<<B_ * H_ * NOFF, 256, 0, stream>>>(x1, x2, out);
    }
}

// Round 12
// 159.592 us; speedup vs baseline: 1.7052x; 1.5839x over previous
//
#include <hip/hip_runtime.h>
#include <hip/hip_bf16.h>

// FlowNetC correlation: B=4, C=256, H=W=96, PAD=MAX_DISP=20, STRIDE2=2, D=21.
// out[b, oy*21+ox, h, w] = (1/C) * sum_c x1[b,c,h,w] * x2[b,c,h+2oy-20,w+2ox-20]
//
// dx even -> split w by parity. Per (b,h,oy,par): out[i,e] = sum_c A[c,i]*B[c,i+e-10]
// (i=w>>1 in [0,48), e=ox). Band GEMM, MFMA 16x16x32 bf16.
//
// ROUND-12: corr_kernel is the VERIFIED R4 text (52.0us, WRITE exactly 63504,
// no spill) — untouched. The target this round is prep_kernel: total-corr has
// been a constant ~110us all session, and prep was never profiled. Old prep:
// per-element div/mod, manual 5-op RNE bit-twiddling per bf16, 16 scalar f32
// LDS reads per 16B output (~900 VALU/thread). New prep: float4 global loads,
// native __bf16 casts (v_cvt_pk_bf16_f32, RNE — bit-identical on non-NaN),
// bf16 LDS tile (pitch 66 ushorts = u32-aligned rows), Phase B = 4 u32 LDS
// reads + 1 uint4 store. ~10x less ALU, 4x fewer load instructions.
//
// h-PAIR corr structure (R4): single 48KB Bs + 16.3KB dual slab = 65.4KB ->
// 2 blocks/CU; STAGE(t+1) after the (e) barrier flies under the store phase +
// partner block's compute; vmcnt(5) counted wait (in-order retirement).

typedef __bf16 bf16x8 __attribute__((ext_vector_type(8)));
typedef float f32x4 __attribute__((ext_vector_type(4)));

#define B_ 4
#define C_ 256
#define H_ 96
#define W_ 96
#define NOFF 21
#define ROWS 96                         // rows per (b,h) image = 2 par * 48
#define IMG_ELEMS (ROWS * C_)           // 24576 ushorts = 48KB
#define X1T_ELEMS (B_ * H_ * IMG_ELEMS) // 9,437,184 ushorts

__device__ __forceinline__ void gl2lds16(const void* g, void* l) {
    __builtin_amdgcn_global_load_lds(
        (const __attribute__((address_space(1))) void*)g,
        (__attribute__((address_space(3))) void*)l, 16, 0, 0);
}

// ---------------------------------------------------------------------------
// Prep: fp32 NCHW -> bf16 swizzled-transposed [b][h][row][chunk^(row&31)]
// row = par*48 + (w>>1), par = w&1; chunk cc holds channels 8cc..8cc+7 at
// position cc ^ (row&31). One block per (b,h,src,c-block-of-64).
// Phase A: float4 loads + native bf16 casts -> LDS tile_us[w][c_local],
// pitch 66 (rows u32-aligned; write banks ~3-way).
// Phase B: chunk (row,tp): s = tp^(row&7); 4 aligned u32 LDS reads
// (2-way max on banks: (w + 4s + e) mod 32 covers all banks per row) +
// one uint4 global store. ccp = ((c0>>3) ^ (row&24)) + tp.
// ---------------------------------------------------------------------------
__global__ __launch_bounds__(256) void prep_kernel(const float* __restrict__ x1,
                                                   const float* __restrict__ x2,
                                                   unsigned short* __restrict__ ws) {
    __shared__ unsigned short tile_us[96 * 66];   // 12,672B
    int bid = blockIdx.x;
    int cblk  = bid & 3;
    int which = (bid >> 2) & 1;
    int bh    = bid >> 3;             // 0..383
    int h = bh % H_;
    int b = bh / H_;
    int c0 = cblk << 6;

    const float* src = (which ? x2 : x1) + ((size_t)(b * C_ + c0) * H_ + h) * W_;
    unsigned short* dst = ws + (size_t)which * X1T_ELEMS + (size_t)(b * H_ + h) * IMG_ELEMS;

    // Phase A: 1536 float4 (64 c x 24 w4). q -> c = q/24, w4 = q%24.
    // Load float4 (16B aligned: h*96 and 4*w4 are multiples of 4), convert
    // with native __bf16 casts (RNE), scatter 4 ushorts to rows 4*w4+e.
#pragma unroll
    for (int it = 0; it < 6; ++it) {
        int q = threadIdx.x + (it << 8);
        int c = q / 24, w4 = q - c * 24;
        const float4 v = *(const float4*)(src + (size_t)c * (H_ * W_) + (w4 << 2));
        unsigned short s0, s1, s2, s3;
        { __bf16 t = (__bf16)v.x; s0 = __builtin_bit_cast(unsigned short, t); }
        { __bf16 t = (__bf16)v.y; s1 = __builtin_bit_cast(unsigned short, t); }
        { __bf16 t = (__bf16)v.z; s2 = __builtin_bit_cast(unsigned short, t); }
        { __bf16 t = (__bf16)v.w; s3 = __builtin_bit_cast(unsigned short, t); }
        int base = (w4 << 2) * 66 + c;
        tile_us[base]           = s0;
        tile_us[base + 66]      = s1;
        tile_us[base + 2 * 66]  = s2;
        tile_us[base + 3 * 66]  = s3;
    }
    __syncthreads();

    // Phase B: 768 chunks (96 rows x 8 tp). Read 8 bf16 (c-consecutive) as
    // 4 u32 (row base w*66 ushorts = w*33 u32, even -> aligned), store 16B.
    const unsigned* tile32 = (const unsigned*)tile_us;
#pragma unroll
    for (int it = 0; it < 3; ++it) {
        int j = threadIdx.x + (it << 8);
        int row = j >> 3, tp = j & 7;
        int par = row / 48, i = row - par * 48;
        int w = 2 * i + par;
        int s = tp ^ (row & 7);
        int rb = w * 33 + (s << 2);
        unsigned v0 = tile32[rb], v1 = tile32[rb + 1], v2 = tile32[rb + 2], v3 = tile32[rb + 3];
        int ccp = (((c0 >> 3) ^ (row & 24)) + tp);
        *(uint4*)((char*)(dst + (size_t)row * C_) + (ccp << 4)) = make_uint4(v0, v1, v2, v3);
    }
}

// ---------------------------------------------------------------------------
// Main: block = (b, h-pair, oy-quarter). 6 waves = (par, mt). 2 blocks/CU.
// (VERIFIED R4 TEXT — unchanged.)
// ---------------------------------------------------------------------------
__global__ __launch_bounds__(384, 3) void corr_kernel(const unsigned short* __restrict__ ws,
                                                      float* __restrict__ out) {
    __shared__ unsigned short Bs[IMG_ELEMS];      // 48KB, single buffer
    __shared__ float sl[2][NOFF][97];             // dual transpose slab (A,B rows)
    static_assert(sizeof(Bs) + sizeof(sl) <= 81920, "need 2 blocks/CU");

    int bid = blockIdx.x;
    int xcd = bid & 7, sidx = bid >> 3;        // XCD-aware: each XCD gets (b, h-half)
    int b  = xcd >> 1;
    int p  = ((xcd & 1) ? 24 : 0) + (sidx >> 2);   // pair index [0,48)
    int og = sidx & 3;                              // oy quarter
    int g = p >> 1, par_h = p & 1;
    int hA = 4 * g + par_h, hB = hA + 2;            // {h mod4 in 0,1} x {+2}
    int olo = (og * NOFF) >> 2;                     // 0,5,10,15
    int ohi = ((og + 1) * NOFF) >> 2;               // 5,10,15,21

    int tid = threadIdx.x;
    int wv = tid >> 6, lane = tid & 63;
    int par = wv & 1, mt = wv >> 1;
    int i0 = mt << 4;
    int n = lane & 15, quad = lane >> 4;

    // Hoisted epilogue addressing: idx = tid + 384j, j < jcnt (5 or 6).
    int jcnt = 5 + (tid < 96 ? 1 : 0);
    int slotj[6], offj[6]; bool mj[6];
#pragma unroll
    for (int j = 0; j < 6; ++j) {
        int idx = tid + j * 384;
        int ox = idx / W_, w = idx - ox * W_;
        slotj[j] = ox * 97 + w;
        offj[j]  = ox * (H_ * W_) + w;
        int w2 = w + 2 * ox - 20;
        mj[j] = (w2 >= 0) & (w2 < W_);
    }

    // A fragments for BOTH rows: loaded once, reused for all t.
    int rowA = par * 48 + i0 + n;
    int keyA = rowA & 31;
    const unsigned short* AgA = ws + (size_t)(b * H_ + hA) * IMG_ELEMS + (size_t)rowA * C_;
    const unsigned short* AgB = ws + (size_t)(b * H_ + hB) * IMG_ELEMS + (size_t)rowA * C_;
    bf16x8 afA[8], afB[8];
#pragma unroll
    for (int ks = 0; ks < 8; ++ks) {
        int o = (((ks << 2) | quad) ^ keyA) << 3;
        afA[ks] = *(const bf16x8*)(AgA + o);
        afB[ks] = *(const bf16x8*)(AgB + o);
    }
    // Drain A loads with a compiler-visible wait BEFORE any DMA is issued so
    // no A-related vmcnt wait lands inside the loop.
    asm volatile("" ::: "memory");
    __builtin_amdgcn_s_waitcnt(0);

    const unsigned short* Bimg = ws + (size_t)X1T_ELEMS + (size_t)(b * H_) * IMG_ELEMS;

    int rowB0 = par * 48 + n;          // u=0 (j 0..15)
    int rowB1 = rowB0 + 16;            // u=1
    int rowB2 = rowB0 + 32;            // u=2
    int keyB0 = rowB0 & 31, keyB1 = rowB1 & 31, keyB2 = rowB2 & 31;

    // Valid oy bands per row (clip h2 in range AND og quarter).
    int aLo = (hA <= 20) ? ((21 - hA) >> 1) : 0; if (aLo < olo) aLo = olo;
    int aHi = ((115 - hA) >> 1) + 1;             if (aHi > ohi) aHi = ohi;
    if (aHi < aLo) aHi = aLo;
    int bLo = (hB <= 20) ? ((21 - hB) >> 1) : 0; if (bLo < olo) bLo = olo;
    int bHi = ((115 - hB) >> 1) + 1;             if (bHi > ohi) bHi = ohi;
    if (bHi < bLo) bHi = bLo;

    // Image parameter t: planeA oy=t (t in [aLo,aHi)), planeB oy=t-1
    // (t in [bLo+1,bHi+1)). Union is contiguous (starts/ends differ by <=1),
    // and every t in it has >=1 valid plane (ledger relies on this).
    int tlo, thi;
    bool ea = (aLo >= aHi), eb = (bLo >= bHi);
    if (ea && eb)      { tlo = 0; thi = 0; }
    else if (ea)       { tlo = bLo + 1; thi = bHi + 1; }
    else if (eb)       { tlo = aLo; thi = aHi; }
    else {
        tlo = (aLo < bLo + 1) ? aLo : bLo + 1;
        thi = (aHi > bHi + 1) ? aHi : bHi + 1;
    }
    int nv = thi - tlo;

    int wvoff  = wv * 8192;            // wave-uniform LDS base offset (6 waves x 8KB)
    int gmaoff = wvoff + lane * 16;    // per-lane global offset

#define STAGE(tt) do {                                                                \
    const char* Bg_ = (const char*)(Bimg + (size_t)(hA + 2 * (tt) - 20) * IMG_ELEMS); \
    _Pragma("unroll")                                                                 \
    for (int c = 0; c < 8; ++c)                                                       \
        gl2lds16(Bg_ + gmaoff + c * 1024, (char*)Bs + wvoff + c * 1024);              \
} while (0)

    // Prologue: stage first image, then zero-fill OOB planes while it flies.
    if (nv > 0) STAGE(tlo);
    asm volatile("" ::: "memory");   // pin: zero-fill stores stay after the STAGE

    for (int oy = olo; oy < ohi; ++oy) {
        if (oy < aLo || oy >= aHi) {
            int outb = ((b * 441 + oy * NOFF) * H_ + hA) * W_;
#pragma unroll
            for (int j = 0; j < 6; ++j) if (j < jcnt) out[outb + offj[j]] = 0.0f;
        }
        if (oy < bLo || oy >= bHi) {
            int outb = ((b * 441 + oy * NOFF) * H_ + hB) * W_;
#pragma unroll
            for (int j = 0; j < 6; ++j) if (j < jcnt) out[outb + offj[j]] = 0.0f;
        }
    }

    const float* slA = &sl[0][0][0];
    const float* slB = &sl[1][0][0];

    for (int k = 0; k < nv; ++k) {
        int t = tlo + k;

        // (b) wait for this image's DMA + barrier. Steady: vmcnt(5) retires
        // P(k) while leaving ~5 of last iter's stores in flight.
        if (k == 0) asm volatile("s_waitcnt vmcnt(0)\ns_barrier" ::: "memory");
        else        asm volatile("s_waitcnt vmcnt(5)\ns_barrier" ::: "memory");

        // (d) batch-load B fragments, then MFMA burst for BOTH A-sets.
        const char* Bsb = (const char*)Bs;
        f32x4 aA0 = {0.f,0.f,0.f,0.f}, aA1 = {0.f,0.f,0.f,0.f}, aA2 = {0.f,0.f,0.f,0.f};
        f32x4 aB0 = {0.f,0.f,0.f,0.f}, aB1 = {0.f,0.f,0.f,0.f}, aB2 = {0.f,0.f,0.f,0.f};

        __builtin_amdgcn_s_setprio(1);
        if (mt == 0) {
            bf16x8 f0[8], f1[8];
#pragma unroll
            for (int ks = 0; ks < 8; ++ks) {
                int ci = (ks << 2) | quad;
                f0[ks] = *(const bf16x8*)(Bsb + rowB0 * 512 + ((ci ^ keyB0) << 4));
                f1[ks] = *(const bf16x8*)(Bsb + rowB1 * 512 + ((ci ^ keyB1) << 4));
            }
#pragma unroll
            for (int ks = 0; ks < 8; ++ks) {
                aA0 = __builtin_amdgcn_mfma_f32_16x16x32_bf16(afA[ks], f0[ks], aA0, 0, 0, 0);
                aA1 = __builtin_amdgcn_mfma_f32_16x16x32_bf16(afA[ks], f1[ks], aA1, 0, 0, 0);
                aB0 = __builtin_amdgcn_mfma_f32_16x16x32_bf16(afB[ks], f0[ks], aB0, 0, 0, 0);
                aB1 = __builtin_amdgcn_mfma_f32_16x16x32_bf16(afB[ks], f1[ks], aB1, 0, 0, 0);
            }
        } else if (mt == 1) {
            bf16x8 f0[8], f1[8], f2[8];
#pragma unroll
            for (int ks = 0; ks < 8; ++ks) {
                int ci = (ks << 2) | quad;
                f0[ks] = *(const bf16x8*)(Bsb + rowB0 * 512 + ((ci ^ keyB0) << 4));
                f1[ks] = *(const bf16x8*)(Bsb + rowB1 * 512 + ((ci ^ keyB1) << 4));
                f2[ks] = *(const bf16x8*)(Bsb + rowB2 * 512 + ((ci ^ keyB2) << 4));
            }
#pragma unroll
            for (int ks = 0; ks < 8; ++ks) {
                aA0 = __builtin_amdgcn_mfma_f32_16x16x32_bf16(afA[ks], f0[ks], aA0, 0, 0, 0);
                aA1 = __builtin_amdgcn_mfma_f32_16x16x32_bf16(afA[ks], f1[ks], aA1, 0, 0, 0);
                aA2 = __builtin_amdgcn_mfma_f32_16x16x32_bf16(afA[ks], f2[ks], aA2, 0, 0, 0);
                aB0 = __builtin_amdgcn_mfma_f32_16x16x32_bf16(afB[ks], f0[ks], aB0, 0, 0, 0);
                aB1 = __builtin_amdgcn_mfma_f32_16x16x32_bf16(afB[ks], f1[ks], aB1, 0, 0, 0);
                aB2 = __builtin_amdgcn_mfma_f32_16x16x32_bf16(afB[ks], f2[ks], aB2, 0, 0, 0);
            }
        } else {
            bf16x8 f1[8], f2[8];
#pragma unroll
            for (int ks = 0; ks < 8; ++ks) {
                int ci = (ks << 2) | quad;
                f1[ks] = *(const bf16x8*)(Bsb + rowB1 * 512 + ((ci ^ keyB1) << 4));
                f2[ks] = *(const bf16x8*)(Bsb + rowB2 * 512 + ((ci ^ keyB2) << 4));
            }
#pragma unroll
            for (int ks = 0; ks < 8; ++ks) {
                aA1 = __builtin_amdgcn_mfma_f32_16x16x32_bf16(afA[ks], f1[ks], aA1, 0, 0, 0);
                aA2 = __builtin_amdgcn_mfma_f32_16x16x32_bf16(afA[ks], f2[ks], aA2, 0, 0, 0);
                aB1 = __builtin_amdgcn_mfma_f32_16x16x32_bf16(afB[ks], f1[ks], aB1, 0, 0, 0);
                aB2 = __builtin_amdgcn_mfma_f32_16x16x32_bf16(afB[ks], f2[ks], aB2, 0, 0, 0);
            }
        }
        __builtin_amdgcn_s_setprio(0);

        // Scatter both planes (in-band cell set is t-invariant, so stale
        // entries are exactly the out-of-range masked ones).
        // C/D: col n = lane&15, row m = quad*4+r. ox = 16*(u+1) + n - (i0+m) - 6.
#pragma unroll
        for (int r = 0; r < 4; ++r) {
            int m = (quad << 2) + r;
            int w = 2 * (i0 + m) + par;
            int oxb = n - i0 - m - 6;
            if (mt != 2) { int ox = 16 + oxb; if (ox >= 0 && ox < NOFF) { sl[0][ox][w] = aA0[r]; sl[1][ox][w] = aB0[r]; } }
            {             int ox = 32 + oxb; if (ox >= 0 && ox < NOFF) { sl[0][ox][w] = aA1[r]; sl[1][ox][w] = aB1[r]; } }
            if (mt != 0) { int ox = 48 + oxb; if (ox >= 0 && ox < NOFF) { sl[0][ox][w] = aA2[r]; sl[1][ox][w] = aB2[r]; } }
        }

        // (e) LDS drain + barrier: slab visible; ALL waves done reading Bs,
        // so the buffer is free for the next image.
        asm volatile("s_waitcnt lgkmcnt(0)\ns_barrier" ::: "memory");

        // (g) stage image t+1 into the (now free) buffer; flies under this
        // block's store phase + the co-resident block's compute phase.
        if (k + 1 < nv) STAGE(t + 1);
        asm volatile("" ::: "memory");   // pin: stores below stay after the STAGE

        // (f) batched slab reads, then plane-masked stores (>=5 per wave,
        // required by the vmcnt ledger; >=1 plane valid per t by construction).
        bool okA = (t >= aLo) & (t < aHi);
        bool okB = (t - 1 >= bLo) & (t - 1 < bHi);
        int outbA = ((b * 441 + t * NOFF) * H_ + hA) * W_;
        int outbB = ((b * 441 + (t - 1) * NOFF) * H_ + hB) * W_;

        float vA[6], vB[6];
#pragma unroll
        for (int j = 0; j < 6; ++j) if (j < jcnt) {
            vA[j] = mj[j] ? slA[slotj[j]] * (1.0f / 256.0f) : 0.0f;
            vB[j] = mj[j] ? slB[slotj[j]] * (1.0f / 256.0f) : 0.0f;
        }
        if (okA) {
#pragma unroll
            for (int j = 0; j < 6; ++j) if (j < jcnt) out[outbA + offj[j]] = vA[j];
        }
        if (okB) {
#pragma unroll
            for (int j = 0; j < 6; ++j) if (j < jcnt) out[outbB + offj[j]] = vB[j];
        }
    }
#undef STAGE
}

// ---------------------------------------------------------------------------
// Fallback (ws too small): direct fp32, slow but correct.
// ---------------------------------------------------------------------------
__global__ __launch_bounds__(256) void corr_fallback(const float* __restrict__ x1,
                                                     const float* __restrict__ x2,
                                                     float* __restrict__ out) {
    int bid = blockIdx.x;
    int oy = bid % NOFF, h = (bid / NOFF) % H_, b = bid / (NOFF * H_);
    int dy = 2 * oy - 20, h2 = h + dy;
    int outbase = ((b * 441 + oy * NOFF) * H_ + h) * W_;
    for (int idx = threadIdx.x; idx < NOFF * W_; idx += 256) {
        int ox = idx / W_, w = idx % W_;
        float acc = 0.f;
        int w2 = w + 2 * ox - 20;
        if (h2 >= 0 && h2 < H_ && w2 >= 0 && w2 < W_) {
            const float* p1 = x1 + (size_t)b * C_ * H_ * W_ + h * W_ + w;
            const float* p2 = x2 + (size_t)b * C_ * H_ * W_ + h2 * W_ + w2;
            for (int c = 0; c < C_; ++c) acc += p1[c * (H_ * W_)] * p2[c * (H_ * W_)];
        }
        out[outbase + ox * (H_ * W_) + w] = acc * (1.0f / 256.0f);
    }
}

extern "C" void kernel_launch(void* const* d_in, const int* in_sizes, int n_in,
                              void* d_out, int out_size, void* d_ws, size_t ws_size,
                              hipStream_t stream) {
    const float* x1 = (const float*)d_in[0];
    const float* x2 = (const float*)d_in[1];
    float* out = (float*)d_out;

    size_t need = (size_t)2 * X1T_ELEMS * sizeof(unsigned short);  // 37.7 MB
    if (ws_size >= need) {
        unsigned short* ws = (unsigned short*)d_ws;
        prep_kernel<<<B_ * H_ * 2 * 4, 256, 0, stream>>>(x1, x2, ws);
        corr_kernel<<<768, 384, 0, stream>>>(ws, out);
    } else {
        corr_fallback<<<B_ * H_ * NOFF, 256, 0, stream>>>(x1, x2, out);
    }
}